// Round 10
// baseline (201.897 us; speedup 1.0000x reference)
//
#include <hip/hip_runtime.h>

// Problem constants (B=64, T=4096, D=100, K=4, BETA=0.25)
#define D_DIM   100
#define K_CODES 4
#define RPB     64      // rows per tile
#define TPB     256     // threads per block (4 waves)
#define PITCH   65      // f32 h^T-tile pitch (words)
#define N_ROWS  262144  // B*T
#define KP      128     // padded K for W hi/lo storage
#define NP      128     // padded N rows of W hi/lo storage
#define TAU     0.25    // d2 margin below which we recompute exactly
#define GRID_GEMM 1024  // fused blocks; each handles 4 tiles (4096 total)
#define NTILES  4

typedef __attribute__((ext_vector_type(8))) __bf16 bf16x8;
typedef __attribute__((ext_vector_type(4))) float  f32x4;

__device__ __forceinline__ unsigned short f2bf_rne(float f) {
    unsigned int u = __builtin_bit_cast(unsigned int, f);
    unsigned int r = u + 0x7fffu + ((u >> 16) & 1u);
    return (unsigned short)(r >> 16);
}
__device__ __forceinline__ float bf2f(unsigned short b) {
    unsigned int u = ((unsigned int)b) << 16;
    return __builtin_bit_cast(float, u);
}

// async global->LDS, 16B per lane: LDS dest = wave-uniform base + lane*16
__device__ __forceinline__ void load_lds16(const float* g, float* s) {
    __builtin_amdgcn_global_load_lds(
        (const __attribute__((address_space(1))) unsigned int*)g,
        (__attribute__((address_space(3))) unsigned int*)s, 16, 0, 0);
}

// stage one 64x100 f32 x-tile (1600 16B chunks) into LDS
__device__ __forceinline__ void stage_x(const float* xg, float* s, int wave, int lane) {
    #pragma unroll
    for (int it = 0; it < 6; ++it) {
        int cbase = it * 256 + wave * 64;                  // wave-uniform chunk base
        load_lds16(xg + (size_t)(cbase + lane) * 4, s + cbase * 4);
    }
    if (wave == 0) load_lds16(xg + (size_t)(1536 + lane) * 4, s + 1536 * 4);
}

// ---------------- pre-kernel: split W1 into padded bf16 hi/lo [NP][KP] ----------------
__global__ __launch_bounds__(256) void split_w_kernel(
    const float* __restrict__ W1,
    unsigned short* __restrict__ Whi, unsigned short* __restrict__ Wlo)
{
    int i = blockIdx.x * 256 + threadIdx.x;
    if (i >= NP * KP) return;
    int n = i / KP, k = i % KP;
    float w = (n < D_DIM && k < D_DIM) ? W1[n * D_DIM + k] : 0.0f;
    unsigned short hb = f2bf_rne(w);
    float lo = w - bf2f(hb);
    Whi[i] = hb;
    Wlo[i] = f2bf_rne(lo);
}

// ---------------- Fused v4: MFMA GEMM+ReLU + VQ, 4 tiles/block, union LDS ----------------
// Per tile: 64 rows, wave owns 32 output cols. GEMM numerics identical to R8/R9;
// VQ = R6's proven f64-distance + margin-guarded exact recompute.
__global__ __launch_bounds__(TPB, 4) void fused_kernel(
    const float* __restrict__ x,
    const unsigned short* __restrict__ Whi, const unsigned short* __restrict__ Wlo,
    const float* __restrict__ b1, const float* __restrict__ cb,
    const float* __restrict__ W1, const int* __restrict__ qflag,
    float* __restrict__ out_h, float* __restrict__ out_pay,
    float* __restrict__ out_aux, double* __restrict__ partials)
{
    // union buffer: phase A = x f32 [64][100] + 32-word tail; phase B = h^T [100][65]
    __shared__ __align__(16) float smem[6500];
    __shared__ double d2s[K_CODES][RPB];
    __shared__ int    idxs[RPB];
    __shared__ unsigned long long flagmask;

    const int tid  = threadIdx.x;
    const int lane = tid & 63;
    const int wave = tid >> 6;
    const int qz = *qflag;   // grid-uniform

    // ---- B fragments + bias: loaded ONCE per block (amortized over 4 tiles) ----
    const int bcol0 = wave * 32;
    const int bn  = lane & 15;
    const int bk  = (lane >> 4) * 8;
    bf16x8 bh[2][4], bl[2][4];
    #pragma unroll
    for (int ct = 0; ct < 2; ++ct) {
        int n = bcol0 + ct * 16 + bn;
        #pragma unroll
        for (int kt = 0; kt < 4; ++kt) {
            int off = n * KP + kt * 32 + bk;
            bh[ct][kt] = *reinterpret_cast<const bf16x8*>(Whi + off);
            bl[ct][kt] = *reinterpret_cast<const bf16x8*>(Wlo + off);
        }
    }
    float bias[2];
    #pragma unroll
    for (int ct = 0; ct < 2; ++ct) {
        int n = bcol0 + ct * 16 + bn;
        bias[ct] = (n < D_DIM) ? b1[n] : 0.0f;
    }
    // zero overread tail once; afterwards it only ever holds finite h^T values (x B-zero-pad = 0)
    if (tid < 32) smem[6400 + tid] = 0.0f;

    const int am = lane & 15;
    const int ak = (lane >> 4) * 8;

    for (int it = 0; it < NTILES; ++it) {
        const int tile = blockIdx.x + it * GRID_GEMM;
        const int rowBase = tile * RPB;
        const float* xg = x + (size_t)rowBase * D_DIM;

        __syncthreads();   // prev tile's LDS reads fully done
        stage_x(xg, smem, wave, lane);
        __syncthreads();   // staging drained (vmcnt(0) before barrier)

        // ---- MFMA: per (rt,kt): LDS f32 read -> in-reg hi/lo cvt -> 6 MFMAs ----
        f32x4 acc[4][2];
        #pragma unroll
        for (int rt = 0; rt < 4; ++rt) {
            acc[rt][0] = (f32x4){0.f, 0.f, 0.f, 0.f};
            acc[rt][1] = (f32x4){0.f, 0.f, 0.f, 0.f};
        }
        #pragma unroll
        for (int rt = 0; rt < 4; ++rt) {
            const int rbase = (rt * 16 + am) * D_DIM;
            #pragma unroll
            for (int kt = 0; kt < 4; ++kt) {
                const float* p = smem + rbase + kt * 32 + ak;   // 16B-aligned
                f32x4 f0 = *reinterpret_cast<const f32x4*>(p);
                f32x4 f1 = *reinterpret_cast<const f32x4*>(p + 4);
                bf16x8 ah, al;
                #pragma unroll
                for (int i = 0; i < 4; ++i) {
                    __bf16 h0 = (__bf16)f0[i];
                    ah[i] = h0;
                    al[i] = (__bf16)(f0[i] - (float)h0);
                    __bf16 h1 = (__bf16)f1[i];
                    ah[4 + i] = h1;
                    al[4 + i] = (__bf16)(f1[i] - (float)h1);
                }
                // exact same pass order as R5-R9 (numerics preserved)
                acc[rt][0] = __builtin_amdgcn_mfma_f32_16x16x32_bf16(ah, bl[0][kt], acc[rt][0], 0, 0, 0);
                acc[rt][0] = __builtin_amdgcn_mfma_f32_16x16x32_bf16(al, bh[0][kt], acc[rt][0], 0, 0, 0);
                acc[rt][0] = __builtin_amdgcn_mfma_f32_16x16x32_bf16(ah, bh[0][kt], acc[rt][0], 0, 0, 0);
                acc[rt][1] = __builtin_amdgcn_mfma_f32_16x16x32_bf16(ah, bl[1][kt], acc[rt][1], 0, 0, 0);
                acc[rt][1] = __builtin_amdgcn_mfma_f32_16x16x32_bf16(al, bh[1][kt], acc[rt][1], 0, 0, 0);
                acc[rt][1] = __builtin_amdgcn_mfma_f32_16x16x32_bf16(ah, bh[1][kt], acc[rt][1], 0, 0, 0);
            }
        }
        __syncthreads();   // x reads done -> safe to overwrite smem with h^T

        // ---- bias+ReLU epilogue into smem as h^T [100][65] ----
        #pragma unroll
        for (int rt = 0; rt < 4; ++rt) {
            int rb = rt * 16 + (lane >> 4) * 4;
            #pragma unroll
            for (int ct = 0; ct < 2; ++ct) {
                int n = bcol0 + ct * 16 + bn;
                if (n < D_DIM) {
                    #pragma unroll
                    for (int i = 0; i < 4; ++i)
                        smem[n * PITCH + rb + i] = fmaxf(acc[rt][ct][i] + bias[ct], 0.0f);
                }
            }
        }
        __syncthreads();   // h^T ready

        if (qz) {
            {   // wave = code k, lane = row; f64 distances (R1/R6-proven)
                const int k = __builtin_amdgcn_readfirstlane(wave & 3);
                const float* crow = cb + k * D_DIM;
                double s = 0.0;
                #pragma unroll
                for (int d = 0; d < D_DIM; ++d) {
                    double dh = (double)smem[d * PITCH + lane] - (double)crow[d];
                    s = fma(dh, dh, s);
                }
                d2s[k][lane] = s;
            }
            __syncthreads();

            if (wave == 0) {   // tentative argmin + margin flag
                double best = d2s[0][lane], second = 1e300;
                int bi = 0;
                #pragma unroll
                for (int k = 1; k < K_CODES; ++k) {
                    double v = d2s[k][lane];
                    if (v < best) { second = best; best = v; bi = k; }
                    else if (v < second) { second = v; }
                }
                idxs[lane] = bi;
                unsigned long long m = __ballot((second - best) < TAU);
                if (lane == 0) flagmask = m;
            }
            __syncthreads();

            {   // flagged rows: wave-cooperative exact recompute (R6-proven)
                unsigned long long m = flagmask;
                int i = 0;
                while (m) {
                    int r = __ffsll((long long)m) - 1;
                    m &= m - 1;
                    if ((i & 3) == wave) {
                        const int e1 = lane;
                        const int e2 = 64 + lane;
                        const bool has2 = (e2 < D_DIM);
                        float z1 = b1[e1];
                        float z2 = has2 ? b1[e2] : 0.0f;
                        const float* xr  = x + (size_t)(rowBase + r) * D_DIM;
                        const float* w1r = W1 + e1 * D_DIM;
                        const float* w2r = W1 + (has2 ? e2 : 0) * D_DIM;
                        #pragma unroll
                        for (int d4 = 0; d4 < 25; ++d4) {
                            float4 xv = reinterpret_cast<const float4*>(xr)[d4];
                            float4 wa = reinterpret_cast<const float4*>(w1r)[d4];
                            z1 = fmaf(xv.x, wa.x, z1); z1 = fmaf(xv.y, wa.y, z1);
                            z1 = fmaf(xv.z, wa.z, z1); z1 = fmaf(xv.w, wa.w, z1);
                            float4 wb = reinterpret_cast<const float4*>(w2r)[d4];
                            z2 = fmaf(xv.x, wb.x, z2); z2 = fmaf(xv.y, wb.y, z2);
                            z2 = fmaf(xv.z, wb.z, z2); z2 = fmaf(xv.w, wb.w, z2);
                        }
                        float h1 = fmaxf(z1, 0.0f);
                        float h2 = fmaxf(z2, 0.0f);
                        double dk[K_CODES];
                        #pragma unroll
                        for (int k = 0; k < K_CODES; ++k) {
                            double p;
                            {
                                double dh = (double)h1 - (double)cb[k * D_DIM + e1];
                                p = dh * dh;
                            }
                            if (has2) {
                                double dh = (double)h2 - (double)cb[k * D_DIM + e2];
                                p = fma(dh, dh, p);
                            }
                            for (int off = 32; off > 0; off >>= 1)
                                p += __shfl_down(p, off);
                            dk[k] = p;
                        }
                        if (lane == 0) {
                            double best = dk[0];
                            int bi = 0;
                            #pragma unroll
                            for (int k = 1; k < K_CODES; ++k)
                                if (dk[k] < best) { best = dk[k]; bi = k; }
                            idxs[r] = bi;
                        }
                    }
                    ++i;
                }
            }
            __syncthreads();

            if (wave == 0) {   // payload + loss partial
                int bi = idxs[lane];
                out_pay[rowBase + lane] = (float)bi;
                double d2min = d2s[bi][lane];
                for (int off = 32; off > 0; off >>= 1)
                    d2min += __shfl_down(d2min, off);
                if (lane == 0) partials[tile] = d2min;
            }

            // ---- combined coalesced writeout: h (LDS transpose) + aux (cb gather) ----
            float* hg = out_h + (size_t)rowBase * D_DIM;
            float* ag = out_aux + (size_t)rowBase * D_DIM;
            for (int v = tid; v < RPB * 25; v += TPB) {
                int r = v / 25;
                int d = (v % 25) * 4;
                reinterpret_cast<float4*>(hg)[v] = make_float4(
                    smem[d * PITCH + r], smem[(d + 1) * PITCH + r],
                    smem[(d + 2) * PITCH + r], smem[(d + 3) * PITCH + r]);
                int bi = idxs[r];
                reinterpret_cast<float4*>(ag)[v] =
                    reinterpret_cast<const float4*>(cb + bi * D_DIM + d)[0];
            }
        } else {
            // quantize==0 path (not exercised; deterministic)
            if (wave == 0) {
                out_pay[rowBase + lane] = 0.0f;
                if (lane == 0) partials[tile] = 0.0;
            }
            float* hg = out_h + (size_t)rowBase * D_DIM;
            float* ag = out_aux + (size_t)rowBase * D_DIM;
            for (int v = tid; v < RPB * 25; v += TPB) {
                int r = v / 25;
                int d = (v % 25) * 4;
                reinterpret_cast<float4*>(hg)[v] = make_float4(
                    smem[d * PITCH + r], smem[(d + 1) * PITCH + r],
                    smem[(d + 2) * PITCH + r], smem[(d + 3) * PITCH + r]);
                reinterpret_cast<float4*>(ag)[v] = make_float4(0, 0, 0, 0);
            }
        }
    }
}

// ---------------- deterministic final loss reduce ----------------
__global__ __launch_bounds__(256) void vq_final_kernel(
    const double* __restrict__ partials, int n, float* __restrict__ loss_out)
{
    __shared__ double sm[256];
    int tid = threadIdx.x;
    double s = 0.0;
    for (int i = tid; i < n; i += 256) s += partials[i];
    sm[tid] = s;
    __syncthreads();
    for (int off = 128; off > 0; off >>= 1) {
        if (tid < off) sm[tid] += sm[tid + off];
        __syncthreads();
    }
    if (tid == 0) {
        double mse = sm[0] / ((double)N_ROWS * (double)D_DIM);
        loss_out[0] = (float)(1.25 * mse);   // (1 + BETA) * mean((h-q)^2)
    }
}

extern "C" void kernel_launch(void* const* d_in, const int* in_sizes, int n_in,
                              void* d_out, int out_size, void* d_ws, size_t ws_size,
                              hipStream_t stream) {
    const float* x  = (const float*)d_in[0];
    const float* W1 = (const float*)d_in[1];
    const float* b1 = (const float*)d_in[2];
    const float* cb = (const float*)d_in[3];
    const int* qflag = (const int*)d_in[4];

    float* out = (float*)d_out;
    const int NR = in_sizes[0] / D_DIM;        // 262144 rows
    const int nblocks = NR / RPB;              // 4096 tiles

    float* out_h    = out;                                  // [NR*100]
    float* out_pay  = out + (size_t)NR * D_DIM;             // [NR]
    float* out_aux  = out_pay + NR;                         // [NR*100]
    float* out_loss = out_aux + (size_t)NR * D_DIM;         // [1]

    double* partials = (double*)d_ws;                       // 32 KB
    const size_t w_off = (size_t)nblocks * sizeof(double);
    unsigned short* Whi = (unsigned short*)((char*)d_ws + w_off);   // 32 KB
    unsigned short* Wlo = Whi + NP * KP;                            // 32 KB

    split_w_kernel<<<(NP * KP) / 256, 256, 0, stream>>>(W1, Whi, Wlo);
    fused_kernel<<<GRID_GEMM, TPB, 0, stream>>>(x, Whi, Wlo, b1, cb, W1, qflag,
                                                out_h, out_pay, out_aux, partials);
    vq_final_kernel<<<1, 256, 0, stream>>>(partials, nblocks, out_loss);
}

// Round 11
// 117.900 us; speedup vs baseline: 1.7124x; 1.7124x over previous
//
#include <hip/hip_runtime.h>

// Problem constants (B=64, T=4096, D=100, K=4, BETA=0.25)
#define D_DIM   100
#define K_CODES 4
#define RPB     64      // rows per vq block
#define TPB     256     // vq threads per block
#define PITCH   65      // f32 h^T-tile pitch (words) for vq
#define N_ROWS  262144  // B*T
#define TAU     0.25    // d2 margin below which we recompute exactly
#define GEMM_TPB 512    // gemm threads per block (8 waves)
#define GEMM_GRID 512   // 4096 waves x 4 tiles = 16384 16-row tiles
#define TILES_PER_WAVE 4
#define NB_PAD  112     // padded W cols (7 col-tiles of 16)

typedef __attribute__((ext_vector_type(8))) __bf16 bf16x8;
typedef __attribute__((ext_vector_type(4))) float  f32x4;

__device__ __forceinline__ unsigned short f2bf_rne(float f) {
    unsigned int u = __builtin_bit_cast(unsigned int, f);
    unsigned int r = u + 0x7fffu + ((u >> 16) & 1u);
    return (unsigned short)(r >> 16);
}
__device__ __forceinline__ float bf2f(unsigned short b) {
    unsigned int u = ((unsigned int)b) << 16;
    return __builtin_bit_cast(float, u);
}

// ---------------- Kernel A (v5): barrier-free streaming MFMA GEMM ----------------
// W1 split to bf16 hi/lo in swizzled LDS (ONE barrier); each wave independently
// streams 4x 16-row tiles: A from global, 84 MFMAs, direct coalesced C stores.
// h numerics bit-identical to R8/R9 (same cvt + same per-acc MFMA chain order).
__global__ __launch_bounds__(GEMM_TPB, 4) void gemm_relu_mfma(
    const float* __restrict__ x, const float* __restrict__ W1,
    const float* __restrict__ b1, float* __restrict__ out_h)
{
    __shared__ unsigned short Bhi[NB_PAD * 128];   // 28 KB, swizzled
    __shared__ unsigned short Blo[NB_PAD * 128];   // 28 KB
    const int tid  = threadIdx.x;
    const int lane = tid & 63;
    const int wave = tid >> 6;
    const int rw = lane & 15;        // A row within tile / B col within ct
    const int kp = lane >> 4;        // k sub-slice 0..3

    // ---- stage W hi/lo into swizzled LDS (values identical to split_w path) ----
    for (int i = tid; i < NB_PAD * 128; i += GEMM_TPB) {
        int n = i >> 7, k = i & 127;
        float w = (n < D_DIM && k < D_DIM) ? W1[n * D_DIM + k] : 0.0f;
        unsigned short hb = f2bf_rne(w);
        unsigned short lb = f2bf_rne(w - bf2f(hb));
        int byte = (n * 256 + k * 2) ^ ((n & 7) << 4);
        *reinterpret_cast<unsigned short*>(reinterpret_cast<char*>(Bhi) + byte) = hb;
        *reinterpret_cast<unsigned short*>(reinterpret_cast<char*>(Blo) + byte) = lb;
    }

    // bias per col-tile (hoisted once)
    float bias[7];
    #pragma unroll
    for (int ct = 0; ct < 7; ++ct) {
        int n = ct * 16 + rw;
        bias[ct] = (n < D_DIM) ? b1[n] : 0.0f;
    }

    __syncthreads();   // THE one barrier: B tiles ready; waves free-run after this

    const int wg = blockIdx.x * 8 + wave;   // global wave id 0..4095

    #pragma unroll
    for (int t = 0; t < TILES_PER_WAVE; ++t) {
        const int tile = wg + t * 4096;     // 16-row tile index
        const float* base = x + (size_t)tile * 16 * D_DIM + rw * D_DIM;

        // ---- A f32 loads (coalesced 128B/row groups); kt=3 tail zero-filled ----
        f32x4 f0[4], f1[4];
        #pragma unroll
        for (int kt = 0; kt < 3; ++kt) {
            const float* p = base + kt * 32 + kp * 8;   // 16B-aligned
            f0[kt] = *reinterpret_cast<const f32x4*>(p);
            f1[kt] = *reinterpret_cast<const f32x4*>(p + 4);
        }
        if (kp == 0)
            f0[3] = *reinterpret_cast<const f32x4*>(base + 96);   // k 96..99
        else
            f0[3] = (f32x4){0.f, 0.f, 0.f, 0.f};
        f1[3] = (f32x4){0.f, 0.f, 0.f, 0.f};                      // k pad -> 0

        // ---- in-register hi/lo cvt (identical to R8/R9) ----
        bf16x8 ah[4], al[4];
        #pragma unroll
        for (int kt = 0; kt < 4; ++kt) {
            #pragma unroll
            for (int i = 0; i < 4; ++i) {
                __bf16 h0 = (__bf16)f0[kt][i];
                ah[kt][i] = h0;
                al[kt][i] = (__bf16)(f0[kt][i] - (float)h0);
                __bf16 h1 = (__bf16)f1[kt][i];
                ah[kt][4 + i] = h1;
                al[kt][4 + i] = (__bf16)(f1[kt][i] - (float)h1);
            }
        }

        // ---- per col-tile: B frags from LDS, 12 MFMAs, bias+ReLU, direct store ----
        const int rb = tile * 16 + kp * 4;          // C rows this lane holds
        const int n = /* col */ 0;                  // computed per ct below
        (void)n;
        #pragma unroll
        for (int ct = 0; ct < 7; ++ct) {
            const int col = ct * 16 + rw;
            bf16x8 bhf[4], blf[4];
            #pragma unroll
            for (int kt = 0; kt < 4; ++kt) {
                int byte = ((ct * 16 + rw) * 256 + (kt * 32 + kp * 8) * 2)
                           ^ (((ct * 16 + rw) & 7) << 4);     // 16B-aligned
                bhf[kt] = *reinterpret_cast<const bf16x8*>(
                    reinterpret_cast<const char*>(Bhi) + byte);
                blf[kt] = *reinterpret_cast<const bf16x8*>(
                    reinterpret_cast<const char*>(Blo) + byte);
            }
            f32x4 a = {0.f, 0.f, 0.f, 0.f};
            #pragma unroll
            for (int kt = 0; kt < 4; ++kt) {   // exact pass order of R5-R9
                a = __builtin_amdgcn_mfma_f32_16x16x32_bf16(ah[kt], blf[kt], a, 0, 0, 0);
                a = __builtin_amdgcn_mfma_f32_16x16x32_bf16(al[kt], bhf[kt], a, 0, 0, 0);
                a = __builtin_amdgcn_mfma_f32_16x16x32_bf16(ah[kt], bhf[kt], a, 0, 0, 0);
            }
            if (col < D_DIM) {
                #pragma unroll
                for (int i = 0; i < 4; ++i) {
                    float h = fmaxf(a[i] + bias[ct], 0.0f);
                    out_h[(size_t)(rb + i) * D_DIM + col] = h;   // 64B-coalesced groups
                }
            }
        }
    }
}

// ---------------- Kernel B: VQ with margin-guarded exact recompute (R6/R9-proven) ----------------
__global__ __launch_bounds__(TPB) void vq_kernel(
    const float* __restrict__ h, const float* __restrict__ x,
    const float* __restrict__ W1, const float* __restrict__ b1,
    const float* __restrict__ cb, const int* __restrict__ qflag,
    float* __restrict__ out_pay, float* __restrict__ out_aux,
    double* __restrict__ partials)
{
    __shared__ float  tile[D_DIM][PITCH];
    __shared__ double d2s[K_CODES][RPB];
    __shared__ int    idxs[RPB];
    __shared__ unsigned long long flagmask;
    const int tid  = threadIdx.x;
    const int lane = tid & 63;
    const int wave = tid >> 6;
    const int blk  = blockIdx.x;
    const int rowBase = blk * RPB;
    const int qz = *qflag;

    if (qz) {
        const float* hgc = h + (size_t)rowBase * D_DIM;
        for (int v = tid; v < (RPB * D_DIM) / 4; v += TPB) {
            float4 val = reinterpret_cast<const float4*>(hgc)[v];
            int r = v / 25;
            int d = (v % 25) * 4;
            tile[d + 0][r] = val.x; tile[d + 1][r] = val.y;
            tile[d + 2][r] = val.z; tile[d + 3][r] = val.w;
        }
        __syncthreads();
        {   // wave = code k, lane = row; f64 distances
            const int k = __builtin_amdgcn_readfirstlane(wave & 3);
            const float* crow = cb + k * D_DIM;
            double s = 0.0;
            #pragma unroll
            for (int d = 0; d < D_DIM; ++d) {
                double dh = (double)tile[d][lane] - (double)crow[d];
                s = fma(dh, dh, s);
            }
            d2s[k][lane] = s;
        }
        __syncthreads();

        if (wave == 0) {   // tentative argmin + margin flag
            double best = d2s[0][lane], second = 1e300;
            int bi = 0;
            #pragma unroll
            for (int k = 1; k < K_CODES; ++k) {
                double v = d2s[k][lane];
                if (v < best) { second = best; best = v; bi = k; }
                else if (v < second) { second = v; }
            }
            idxs[lane] = bi;
            unsigned long long m = __ballot((second - best) < TAU);
            if (lane == 0) flagmask = m;
        }
        __syncthreads();

        {   // flagged rows: wave-cooperative exact recompute (R1 arithmetic)
            unsigned long long m = flagmask;
            int i = 0;
            while (m) {
                int r = __ffsll((long long)m) - 1;
                m &= m - 1;
                if ((i & 3) == wave) {
                    const int e1 = lane;
                    const int e2 = 64 + lane;
                    const bool has2 = (e2 < D_DIM);
                    float z1 = b1[e1];
                    float z2 = has2 ? b1[e2] : 0.0f;
                    const float* xr  = x + (size_t)(rowBase + r) * D_DIM;
                    const float* w1r = W1 + e1 * D_DIM;
                    const float* w2r = W1 + (has2 ? e2 : 0) * D_DIM;
                    #pragma unroll
                    for (int d4 = 0; d4 < 25; ++d4) {
                        float4 xv = reinterpret_cast<const float4*>(xr)[d4];
                        float4 wa = reinterpret_cast<const float4*>(w1r)[d4];
                        z1 = fmaf(xv.x, wa.x, z1); z1 = fmaf(xv.y, wa.y, z1);
                        z1 = fmaf(xv.z, wa.z, z1); z1 = fmaf(xv.w, wa.w, z1);
                        float4 wb = reinterpret_cast<const float4*>(w2r)[d4];
                        z2 = fmaf(xv.x, wb.x, z2); z2 = fmaf(xv.y, wb.y, z2);
                        z2 = fmaf(xv.z, wb.z, z2); z2 = fmaf(xv.w, wb.w, z2);
                    }
                    float h1 = fmaxf(z1, 0.0f);
                    float h2 = fmaxf(z2, 0.0f);
                    double dk[K_CODES];
                    #pragma unroll
                    for (int k = 0; k < K_CODES; ++k) {
                        double p;
                        {
                            double dh = (double)h1 - (double)cb[k * D_DIM + e1];
                            p = dh * dh;
                        }
                        if (has2) {
                            double dh = (double)h2 - (double)cb[k * D_DIM + e2];
                            p = fma(dh, dh, p);
                        }
                        for (int off = 32; off > 0; off >>= 1)
                            p += __shfl_down(p, off);
                        dk[k] = p;
                    }
                    if (lane == 0) {
                        double best = dk[0];
                        int bi = 0;
                        #pragma unroll
                        for (int k = 1; k < K_CODES; ++k)
                            if (dk[k] < best) { best = dk[k]; bi = k; }
                        idxs[r] = bi;
                    }
                }
                ++i;
            }
        }
        __syncthreads();

        if (wave == 0) {   // payload + loss partial
            int bi = idxs[lane];
            out_pay[rowBase + lane] = (float)bi;
            double d2min = d2s[bi][lane];
            for (int off = 32; off > 0; off >>= 1)
                d2min += __shfl_down(d2min, off);
            if (lane == 0) partials[blk] = d2min;
        }

        float* ag = out_aux + (size_t)rowBase * D_DIM;
        for (int v = tid; v < (RPB * D_DIM) / 4; v += TPB) {
            int r = v / 25;
            int d = (v % 25) * 4;
            int bi = idxs[r];
            reinterpret_cast<float4*>(ag)[v] =
                reinterpret_cast<const float4*>(cb + bi * D_DIM + d)[0];
        }
    } else {
        if (wave == 0) {
            out_pay[rowBase + lane] = 0.0f;
            if (lane == 0) partials[blk] = 0.0;
        }
        float* ag = out_aux + (size_t)rowBase * D_DIM;
        for (int v = tid; v < (RPB * D_DIM) / 4; v += TPB)
            reinterpret_cast<float4*>(ag)[v] = make_float4(0, 0, 0, 0);
    }
}

// ---------------- deterministic final loss reduce ----------------
__global__ __launch_bounds__(256) void vq_final_kernel(
    const double* __restrict__ partials, int n, float* __restrict__ loss_out)
{
    __shared__ double sm[256];
    int tid = threadIdx.x;
    double s = 0.0;
    for (int i = tid; i < n; i += 256) s += partials[i];
    sm[tid] = s;
    __syncthreads();
    for (int off = 128; off > 0; off >>= 1) {
        if (tid < off) sm[tid] += sm[tid + off];
        __syncthreads();
    }
    if (tid == 0) {
        double mse = sm[0] / ((double)N_ROWS * (double)D_DIM);
        loss_out[0] = (float)(1.25 * mse);   // (1 + BETA) * mean((h-q)^2)
    }
}

extern "C" void kernel_launch(void* const* d_in, const int* in_sizes, int n_in,
                              void* d_out, int out_size, void* d_ws, size_t ws_size,
                              hipStream_t stream) {
    const float* x  = (const float*)d_in[0];
    const float* W1 = (const float*)d_in[1];
    const float* b1 = (const float*)d_in[2];
    const float* cb = (const float*)d_in[3];
    const int* qflag = (const int*)d_in[4];

    float* out = (float*)d_out;
    const int NR = in_sizes[0] / D_DIM;        // 262144 rows
    const int nblocks = NR / RPB;              // 4096 vq tiles

    float* out_h    = out;                                  // [NR*100]
    float* out_pay  = out + (size_t)NR * D_DIM;             // [NR]
    float* out_aux  = out_pay + NR;                         // [NR*100]
    float* out_loss = out_aux + (size_t)NR * D_DIM;         // [1]
    double* partials = (double*)d_ws;                       // 32 KB

    gemm_relu_mfma<<<GEMM_GRID, GEMM_TPB, 0, stream>>>(x, W1, b1, out_h);
    vq_kernel<<<nblocks, TPB, 0, stream>>>(out_h, x, W1, b1, cb, qflag,
                                           out_pay, out_aux, partials);
    vq_final_kernel<<<1, 256, 0, stream>>>(partials, nblocks, out_loss);
}